// Round 18
// baseline (94.344 us; speedup 1.0000x reference)
//
#include <hip/hip_runtime.h>
#include <math.h>

#define B_   2
#define L_   2048
#define D_   1024
#define H_   16
#define G_   4
#define Hd_  64
#define WIN_ 256

typedef float f4 __attribute__((ext_vector_type(4)));
typedef float f32x4 __attribute__((ext_vector_type(4)));
typedef short s16x8 __attribute__((ext_vector_type(8)));
typedef ushort u16x4 __attribute__((ext_vector_type(4)));

// ln(10000)/32
#define ROPE_LN 0.28782313662425575

__device__ __forceinline__ float bf2f(ushort u) {
    union { uint i; float f; } c; c.i = ((uint)u) << 16; return c.f;
}
__device__ __forceinline__ ushort f2bf(float f) {
    union { float f; uint i; } c; c.f = f;
    return (ushort)((c.i + 0x7FFFu + ((c.i >> 16) & 1u)) >> 16);
}
// pack two f32 -> two bf16 (RNE), single instruction
__device__ __forceinline__ uint cvtpk(float lo, float hi) {
    uint r;
    asm("v_cvt_pk_bf16_f32 %0, %1, %2" : "=v"(r) : "v"(lo), "v"(hi));
    return r;
}

// async global->LDS 16B copy: lds dest is wave-uniform base + lane*16
__device__ __forceinline__ void async_copy16(const ushort* g, ushort* l) {
    __builtin_amdgcn_global_load_lds(
        (const __attribute__((address_space(1))) void*)g,
        (__attribute__((address_space(3))) void*)l,
        16, 0, 0);
}

// ---------------------------------------------------------------------------
// Fused prep: blocks [0,4096) x-cast; [4096,5120) weight transpose+cast;
// [5120,5376) RoPE sin/cos table.
// ---------------------------------------------------------------------------
__global__ __launch_bounds__(256) void k_prep_all(
    const float* __restrict__ x, ushort* __restrict__ xb,
    const float* __restrict__ Wq, const float* __restrict__ Wk,
    const float* __restrict__ Wv, const float* __restrict__ Wo,
    ushort* __restrict__ Wt, ushort* __restrict__ Wot,
    float* __restrict__ sct)
{
    __shared__ __align__(16) float Ts[64][68];
    const int bid = blockIdx.x;
    const int tid = threadIdx.x;

    if (bid < 4096) {                       // ---- x cast ----
        const int idx = bid * 256 + tid;
        f4 v = ((const f4*)x)[idx];
        u16x4 o;
        o[0] = f2bf(v[0]); o[1] = f2bf(v[1]); o[2] = f2bf(v[2]); o[3] = f2bf(v[3]);
        ((u16x4*)xb)[idx] = o;
        return;
    }
    if (bid >= 5120) {                      // ---- sin/cos table ----
        const int idx = (bid - 5120) * 256 + tid;
        const int l = idx >> 5, m = idx & 31;
        const float invf = (float)exp(-ROPE_LN * (double)m);
        const float a = (float)l * invf;
        sct[l * 64 + m]      = cosf(a);
        sct[l * 64 + 32 + m] = sinf(a);
        return;
    }
    // ---- weight transpose+cast ----
    const int t = bid - 4096;
    const int z = t >> 8;
    const float* W; ushort* dst; int N, rowoff;
    if (z == 0)      { W = Wq; N = 1024; dst = Wt;  rowoff = 0;    }
    else if (z == 1) { W = Wk; N = 256;  dst = Wt;  rowoff = 1024; }
    else if (z == 2) { W = Wv; N = 256;  dst = Wt;  rowoff = 1280; }
    else             { W = Wo; N = 1024; dst = Wot; rowoff = 0;    }
    const int k0 = ((t >> 4) & 15) << 6;
    const int n0 = (t & 15) << 6;
    if (n0 >= N) return;
    const int rr = tid >> 4, cc4 = (tid & 15) << 2;
#pragma unroll
    for (int i = 0; i < 4; ++i) {
        const int r = rr + i * 16;
        *(f4*)&Ts[r][cc4] = *(const f4*)&W[(size_t)(k0 + r) * N + n0 + cc4];
    }
    __syncthreads();
#pragma unroll
    for (int i = 0; i < 4; ++i) {
        const int tr = rr + i * 16;
        u16x4 pk;
#pragma unroll
        for (int j = 0; j < 4; ++j) pk[j] = f2bf(Ts[cc4 + j][tr]);
        *(u16x4*)&dst[(size_t)(rowoff + n0 + tr) * 1024 + k0 + cc4] = pk;
    }
}

// ---------------------------------------------------------------------------
// bf16 MFMA GEMM: C[M,N] = A[M,1024] @ Bt[N,1024]^T.  128x64 tile, BK=64,
// global_load_lds(16B) staging, XOR-slot swizzle.
// mode 0: QKV epilogue (bias + RoPE from LDS table + scatter q/k/Vt bf16)
// mode 1: out-proj epilogue (bias + fp32 store)
// ---------------------------------------------------------------------------
__global__ __launch_bounds__(256) void k_gemm_bf16(
    const ushort* __restrict__ A, const ushort* __restrict__ Bt, int mode,
    const float* __restrict__ b0, const float* __restrict__ b1,
    const float* __restrict__ b2, const float* __restrict__ sct,
    ushort* __restrict__ qo, ushort* __restrict__ ko, ushort* __restrict__ vt,
    float* __restrict__ outp)
{
    __shared__ __align__(16) ushort LDSbuf[16384];    // As 8192 | Bs 4096 | (RoPE tab reuse)
    ushort* As = LDSbuf;
    ushort* Bs = LDSbuf + 8192;

    const int tid = threadIdx.x;
    const int wv = tid >> 6, lane = tid & 63, lr = lane & 15, lg = lane >> 4;
    const int wm = wv >> 1, wn = wv & 1;
    const int rblk = blockIdx.x << 7, cblk = blockIdx.y << 6;

    const ushort* agp[4]; ushort* alds[4];
#pragma unroll
    for (int i = 0; i < 4; ++i) {
        const int slot = wv * 256 + i * 64 + lane;
        const int r = slot >> 3, c = slot & 7;
        const int ss = c ^ (r & 7);
        agp[i] = A + (size_t)(rblk + r) * 1024 + ss * 8;
        alds[i] = As + (wv * 256 + i * 64) * 8;       // wave-uniform base
    }
    const ushort* bgp[2]; ushort* blds[2];
#pragma unroll
    for (int i = 0; i < 2; ++i) {
        const int slot = wv * 128 + i * 64 + lane;
        const int r = slot >> 3, c = slot & 7;
        const int ss = c ^ (r & 7);
        bgp[i] = Bt + (size_t)(cblk + r) * 1024 + ss * 8;
        blds[i] = Bs + (wv * 128 + i * 64) * 8;
    }

    f32x4 acc[4][2];
#pragma unroll
    for (int m = 0; m < 4; ++m)
#pragma unroll
        for (int n = 0; n < 2; ++n) acc[m][n] = (f32x4)0.f;

    for (int kt = 0; kt < 16; ++kt) {
        if (kt) __syncthreads();
        const int ko_ = kt * 64;
#pragma unroll
        for (int i = 0; i < 4; ++i) async_copy16(agp[i] + ko_, alds[i]);
#pragma unroll
        for (int i = 0; i < 2; ++i) async_copy16(bgp[i] + ko_, blds[i]);
        __syncthreads();

#pragma unroll
        for (int ks = 0; ks < 2; ++ks) {
            s16x8 aF[4], bF[2];
#pragma unroll
            for (int m = 0; m < 4; ++m) {
                const int r = wm * 64 + m * 16 + lr;
                const int c = (ks * 4 + lg) ^ (r & 7);
                aF[m] = *(const s16x8*)&As[r * 64 + c * 8];
            }
#pragma unroll
            for (int n = 0; n < 2; ++n) {
                const int r = wn * 32 + n * 16 + lr;
                const int c = (ks * 4 + lg) ^ (r & 7);
                bF[n] = *(const s16x8*)&Bs[r * 64 + c * 8];
            }
            __builtin_amdgcn_s_setprio(1);
#pragma unroll
            for (int m = 0; m < 4; ++m)
#pragma unroll
                for (int n = 0; n < 2; ++n)
                    acc[m][n] = __builtin_amdgcn_mfma_f32_16x16x32_bf16(aF[m], bF[n], acc[m][n], 0, 0, 0);
            __builtin_amdgcn_s_setprio(0);
        }
    }

    // ---- epilogue ----
    if (mode == 0) {
        const bool dorope = (cblk < 1280);
        float* tab = (float*)LDSbuf;
        if (dorope) {
            __syncthreads();
            const float* srcT = sct + (size_t)(rblk & 2047) * 64;
            for (int i = tid; i < 2048; i += 256)
                ((f4*)tab)[i] = ((const f4*)srcT)[i];
            __syncthreads();
        }
#pragma unroll
        for (int m = 0; m < 4; ++m) {
            const int row0 = rblk + wm * 64 + m * 16 + (lg << 2);
            const int bb = row0 >> 11, l0 = row0 & 2047;
            const int ll0 = row0 - rblk;
#pragma unroll
            for (int n = 0; n < 2; ++n) {
                const int col = cblk + wn * 32 + n * 16 + lr;
                float v_[4];
                const float bi = (col < 1024) ? b0[col]
                               : (col < 1280) ? b1[col - 1024] : b2[col - 1280];
#pragma unroll
                for (int rg = 0; rg < 4; ++rg) v_[rg] = acc[m][n][rg] + bi;
                if (dorope) {
                    const int mI = col & 31;
                    const float sgn = (lr & 1) ? 1.f : -1.f;
#pragma unroll
                    for (int rg = 0; rg < 4; ++rg) {
                        const float part = __shfl_xor(v_[rg], 1);
                        const float c_ = tab[(ll0 + rg) * 64 + mI];
                        const float s_ = tab[(ll0 + rg) * 64 + 32 + mI];
                        v_[rg] = v_[rg] * c_ + sgn * part * s_;
                    }
                }
                if (col < 1024) {
                    const int h = col >> 6, d = col & 63;
                    ushort* p = qo + (((size_t)(bb * 16 + h)) * 2048 + l0) * 64 + d;
#pragma unroll
                    for (int rg = 0; rg < 4; ++rg)
                        p[(size_t)rg * 64] = f2bf(v_[rg] * 0.125f);
                } else if (col < 1280) {
                    const int cl = col - 1024, g = cl >> 6, d = cl & 63;
                    ushort* p = ko + (((size_t)(bb * 4 + g)) * 2048 + l0) * 64 + d;
#pragma unroll
                    for (int rg = 0; rg < 4; ++rg)
                        p[(size_t)rg * 64] = f2bf(v_[rg]);
                } else {
                    const int cl = col - 1280, g = cl >> 6, d = cl & 63;
                    u16x4 pk;
#pragma unroll
                    for (int rg = 0; rg < 4; ++rg) pk[rg] = f2bf(v_[rg]);
                    *(u16x4*)(vt + ((size_t)(bb * 4 + g) * 64 + d) * 2048 + l0) = pk;
                }
            }
        }
    } else {
#pragma unroll
        for (int m = 0; m < 4; ++m) {
            const int row0 = rblk + wm * 64 + m * 16 + (lg << 2);
#pragma unroll
            for (int n = 0; n < 2; ++n) {
                const int col = cblk + wn * 32 + n * 16 + lr;
                const float bi = b0[col];
#pragma unroll
                for (int rg = 0; rg < 4; ++rg)
                    outp[(size_t)(row0 + rg) * 1024 + col] = acc[m][n][rg] + bi;
            }
        }
    }
}

// ---------------------------------------------------------------------------
// Windowed flash attention + merged full-row path (R17) + T13 defer-max:
// when __all(mx <= mrun + 8) keep the old reference max -> skip al-exp,
// the 4 shfl broadcasts, and the 16 acc rescale muls (wave-uniform branch).
// P magnitudes bounded by e^8 (bf16 relative precision unaffected).
// blocks x<128: windowed path; blocks x in [128,144): full-row global rows.
// ---------------------------------------------------------------------------
__global__ __launch_bounds__(256, 4) void k_attn_win(
    const ushort* __restrict__ qb, const ushort* __restrict__ kb,
    const ushort* __restrict__ vtb, const int* __restrict__ gpos,
    ushort* __restrict__ aout)
{
    __shared__ __align__(16) ushort Ks[2][4096];   // 64r x 8 slots x 8 (8KB/buf)
    __shared__ __align__(16) ushort Vs[2][4096];
    __shared__ ushort Pl[4][1024];                 // per-wave P tile (swizzled)

    const int tid  = threadIdx.x;

    if (blockIdx.x >= 128) {
        // ================= merged full-row path =================
        const int e  = blockIdx.x - 128;           // 0..15
        const int gi = e >> 2;
        const int g  = blockIdx.y;
        const int h  = (g << 2) | (e & 3);
        const int b  = blockIdx.z;
        const int wv = tid >> 6, lane = tid & 63;
        const int lq = gpos[gi];
        for (int j = 0; j < gi; ++j)
            if (gpos[j] == lq) return;             // duplicate -> done

        float* Ps   = (float*)&Ks[0][0];           // 8 KB
        float* qrow = (float*)&Vs[0][0];           // 256 B
        float* red  = qrow + 64;                   // 16 B
        float* pacc = qrow + 128;                  // 1 KB: pacc[ch*64+d]

        const ushort* kbase = kb  + ((size_t)b * G_ + g) * (size_t)L_ * Hd_;
        const ushort* vbase = vtb + ((size_t)b * G_ + g) * (size_t)Hd_ * L_;

        if (tid < 64) qrow[tid] = bf2f(qb[(((size_t)b * H_ + h) * L_ + lq) * Hd_ + tid]);
        __syncthreads();

        float sc[8]; float lmax = -INFINITY;
#pragma unroll
        for (int c = 0; c < 8; ++c) {
            const int s = tid + (c << 8);
            const s16x8* kr = (const s16x8*)(kbase + (size_t)s * Hd_);
            float dot = 0.f;
#pragma unroll
            for (int d8 = 0; d8 < 8; ++d8) {
                s16x8 kv = kr[d8];
#pragma unroll
                for (int j = 0; j < 8; ++j) dot += qrow[d8 * 8 + j] * bf2f((ushort)kv[j]);
            }
            sc[c] = dot; lmax = fmaxf(lmax, dot);
        }
#pragma unroll
        for (int o = 32; o; o >>= 1) lmax = fmaxf(lmax, __shfl_xor(lmax, o));
        if (lane == 0) red[wv] = lmax;
        __syncthreads();
        const float M = fmaxf(fmaxf(red[0], red[1]), fmaxf(red[2], red[3]));
        __syncthreads();

        float ls = 0.f;
#pragma unroll
        for (int c = 0; c < 8; ++c) {
            const float p = __expf(sc[c] - M);
            Ps[tid + (c << 8)] = p;
            ls += p;
        }
#pragma unroll
        for (int o = 32; o; o >>= 1) ls += __shfl_xor(ls, o);
        if (lane == 0) red[wv] = ls;
        __syncthreads();
        const float S = red[0] + red[1] + red[2] + red[3];

        const int d = tid & 63, ch = tid >> 6;
        const ushort* vr = vbase + (size_t)d * L_ + (ch << 9);
        float a = 0.f;
        for (int s8 = 0; s8 < 64; ++s8) {
            s16x8 vv = ((const s16x8*)vr)[s8];
            const float* pp = &Ps[(ch << 9) + (s8 << 3)];
#pragma unroll
            for (int j = 0; j < 8; ++j) a += pp[j] * bf2f((ushort)vv[j]);
        }
        pacc[ch * 64 + d] = a;
        __syncthreads();
        if (tid < 64) {
            const float sum = pacc[0 * 64 + tid] + pacc[1 * 64 + tid]
                            + pacc[2 * 64 + tid] + pacc[3 * 64 + tid];
            aout[(((size_t)b * L_ + lq) * H_ + h) * Hd_ + tid] = f2bf(sum / S);
        }
        return;
    }

    // ================= windowed path =================
    const int wv   = tid >> 6, lane = tid & 63;
    const int lr   = lane & 15, lg = lane >> 4;
    const int qt = ((blockIdx.x & 7) << 4) | (blockIdx.x >> 3);  // XCD swizzle
    const int g = blockIdx.y, b = blockIdx.z;
    const int h  = (g << 2) + wv;             // this wave's head
    const int q0w = qt << 4;                  // 16 queries/block
    const int qpos = q0w + lr;                // this lane's softmax row

    const ushort* qp = qb  + (((size_t)b * H_ + h) * L_ + q0w) * Hd_;
    const ushort* kp = kb  + ((size_t)b * G_ + g) * (size_t)L_ * Hd_;
    const ushort* vp = vtb + ((size_t)b * G_ + g) * (size_t)Hd_ * L_;
    char* rowp = (char*)&Pl[wv][0] + (lr << 7);
    const int swz = (lr & 7) << 4;

    // staging geometry: 512 slots (64 rows x 8 x 16B) per matrix; this wave
    // covers slots [wv*128, wv*128+128) via 2 insts; lane -> slot base+lane.
    int sr[2], ssk[2];
    ushort* kl[2]; ushort* vl[2];
#pragma unroll
    for (int i = 0; i < 2; ++i) {
        const int slot = wv * 128 + i * 64 + lane;
        const int r = slot >> 3, c = slot & 7;
        sr[i] = r; ssk[i] = c ^ (r & 7);           // inverse-swizzled src slot
        kl[i] = ((ushort*)Ks) + (wv * 128 + i * 64) * 8;
        vl[i] = ((ushort*)Vs) + (wv * 128 + i * 64) * 8;
    }

#define STAGE(CUR, S0_) do {                                                  \
    _Pragma("unroll") for (int i = 0; i < 2; ++i) {                           \
        async_copy16(kp + ((size_t)(S0_) + sr[i]) * 64 + ssk[i] * 8,          \
                     kl[i] + (CUR) * 4096);                                   \
        async_copy16(vp + (size_t)sr[i] * 2048 + (S0_) + ssk[i] * 8,          \
                     vl[i] + (CUR) * 4096);                                   \
    } } while (0)

    const s16x8* qr = (const s16x8*)(qp + (size_t)lr * Hd_);
    const s16x8 qf0 = qr[lg], qf1 = qr[lg + 4];

    int gall[4];
#pragma unroll
    for (int j = 0; j < 4; ++j) gall[j] = gpos[j];
    bool uniq[4];
    uniq[0] = true;
    uniq[1] = (gall[1] != gall[0]);
    uniq[2] = (gall[2] != gall[0]) && (gall[2] != gall[1]);
    uniq[3] = (gall[3] != gall[0]) && (gall[3] != gall[1]) && (gall[3] != gall[2]);

    f32x4 acc_o[4];
#pragma unroll
    for (int j = 0; j < 4; ++j) acc_o[j] = (f32x4)0.f;
    float mrun = -INFINITY, lrun = 0.f;

    // window key tiles for queries [q0w, q0w+15]:
    const int t_lo = (q0w - WIN_ > 0) ? ((q0w - WIN_) >> 6) : 0;
    const int t_hi_f = (q0w + 15 + WIN_) >> 6;
    const int t_hi = (t_hi_f < (L_ >> 6) - 1) ? t_hi_f : (L_ >> 6) - 1;

    const int kc0 = lg ^ (lr & 7);            // swizzled read slots
    const int kc1 = (lg + 4) ^ (lr & 7);

    int cur = 0;
    STAGE(0, t_lo << 6);

    for (int t = t_lo; t <= t_hi; ++t) {
        const int s0 = t << 6;
        __syncthreads();                      // buf[cur] staged; prev consume done
        if (t < t_hi) STAGE(cur ^ 1, (t + 1) << 6);

        const ushort* Kb = ((const ushort*)Ks) + cur * 4096;
        const ushort* Vb = ((const ushort*)Vs) + cur * 4096;

        // ---- QK^T swapped, K frags from LDS ----
        f32x4 s[4];
#pragma unroll
        for (int gk = 0; gk < 4; ++gk) {
            const int gr = gk * 16 + lr;
            s16x8 kf0 = *(const s16x8*)&Kb[(gr * 8 + kc0) * 8];
            s16x8 kf1 = *(const s16x8*)&Kb[(gr * 8 + kc1) * 8];
            f32x4 tq = __builtin_amdgcn_mfma_f32_16x16x32_bf16(kf0, qf0, (f32x4)0.f, 0, 0, 0);
            s[gk]    = __builtin_amdgcn_mfma_f32_16x16x32_bf16(kf1, qf1, tq, 0, 0, 0);
        }

        // ---- V frags from LDS ----
        s16x8 vf0[4], vf1[4];
#pragma unroll
        for (int dg = 0; dg < 4; ++dg) {
            const int vrw = dg * 16 + lr;
            vf0[dg] = *(const s16x8*)&Vb[(vrw * 8 + kc0) * 8];
            vf1[dg] = *(const s16x8*)&Vb[(vrw * 8 + kc1) * 8];
        }

        // ---- mask (edge tiles only; wave-uniform test) ----
        if (s0 < q0w - 241 || s0 > q0w + 193) {
#pragma unroll
            for (int gk = 0; gk < 4; ++gk)
#pragma unroll
                for (int r2 = 0; r2 < 4; ++r2) {
                    const int key = s0 + gk * 16 + (lg << 2) + r2;
                    const int dlt = qpos - key;
                    if (dlt > WIN_ || dlt < -WIN_) s[gk][r2] = -INFINITY;
                }
        }

        // ---- online softmax: in-lane tree + 2 shfl; T13 defer-max ----
        float mx = fmaxf(fmaxf(s[0][0], s[0][1]), fmaxf(s[0][2], s[0][3]));
#pragma unroll
        for (int gk = 1; gk < 4; ++gk)
            mx = fmaxf(mx, fmaxf(fmaxf(s[gk][0], s[gk][1]), fmaxf(s[gk][2], s[gk][3])));
        mx = fmaxf(mx, __shfl_xor(mx, 16));
        mx = fmaxf(mx, __shfl_xor(mx, 32));

        const bool skip = __all(mx <= mrun + 8.f);   // mrun=-inf -> false
        const float mref = skip ? mrun : fmaxf(mrun, mx);

        float rs = 0.f;
        uint pk0[4], pk1[4];
#pragma unroll
        for (int gk = 0; gk < 4; ++gk) {
            const float p0 = __expf(s[gk][0] - mref);
            const float p1 = __expf(s[gk][1] - mref);
            const float p2 = __expf(s[gk][2] - mref);
            const float p3 = __expf(s[gk][3] - mref);
            rs += (p0 + p1) + (p2 + p3);
            pk0[gk] = cvtpk(p0, p1);
            pk1[gk] = cvtpk(p2, p3);
        }
        rs += __shfl_xor(rs, 16);
        rs += __shfl_xor(rs, 32);

        if (skip) {
            lrun += rs;                        // reference max unchanged
        } else {
            const float al = __expf(mrun - mref);   // -inf -> 0, safe
            lrun = lrun * al + rs;
            mrun = mref;
            f32x4 al4;
#pragma unroll
            for (int r = 0; r < 4; ++r)
                al4[r] = __shfl(al, (lane & 48) + (lg << 2) + r);
#pragma unroll
            for (int j = 0; j < 4; ++j) acc_o[j] *= al4;
        }

        // ---- P write: 4x 8B per lane, swizzled ----
#pragma unroll
        for (int gk = 0; gk < 4; ++gk) {
            uint2 w; w.x = pk0[gk]; w.y = pk1[gk];
            *(uint2*)(rowp + (((gk << 5) + (lg << 3)) ^ swz)) = w;
        }

        // ---- PV ----
        const s16x8 pa0 = *(const s16x8*)(rowp + ((lg << 4) ^ swz));
        const s16x8 pa1 = *(const s16x8*)(rowp + ((64 + (lg << 4)) ^ swz));
        __builtin_amdgcn_s_setprio(1);
#pragma unroll
        for (int dg = 0; dg < 4; ++dg) {
            acc_o[dg] = __builtin_amdgcn_mfma_f32_16x16x32_bf16(pa0, vf0[dg], acc_o[dg], 0, 0, 0);
            acc_o[dg] = __builtin_amdgcn_mfma_f32_16x16x32_bf16(pa1, vf1[dg], acc_o[dg], 0, 0, 0);
        }
        __builtin_amdgcn_s_setprio(0);

        cur ^= 1;
    }

    // ---- global-column pseudo-tile (per wave, direct global; tiny) ----
    {
        const s16x8* kr = (const s16x8*)(kp + (size_t)gall[lr & 3] * 64);
        s16x8 kf0 = kr[lg], kf1 = kr[lg + 4];
        f32x4 tq = __builtin_amdgcn_mfma_f32_16x16x32_bf16(kf0, qf0, (f32x4)0.f, 0, 0, 0);
        f32x4 sv = __builtin_amdgcn_mfma_f32_16x16x32_bf16(kf1, qf1, tq, 0, 0, 0);

        // k = lg*4+r2 -> key gall[r2]; valid only lg==0 & unique & outside win
#pragma unroll
        for (int r2 = 0; r2 < 4; ++r2) {
            bool valid = (lg == 0) && uniq[r2];
            const int dlt = qpos - gall[r2];
            valid = valid && ((dlt > WIN_) || (dlt < -WIN_));
            if (!valid) sv[r2] = -INFINITY;
        }

        float mx = fmaxf(fmaxf(sv[0], sv[1]), fmaxf(sv[2], sv[3]));
        mx = fmaxf(mx, __shfl_xor(mx, 16));
        mx = fmaxf(mx, __shfl_xor(mx, 32));
        const float mn = fmaxf(mrun, mx);
        const float al = __expf(mrun - mn);
        const float p0 = __expf(sv[0] - mn);
        const float p1 = __expf(sv[1] - mn);
        const float p2 = __expf(sv[2] - mn);
        const float p3 = __expf(sv[3] - mn);
        float rs = (p0 + p1) + (p2 + p3);
        rs += __shfl_xor(rs, 16);
        rs += __shfl_xor(rs, 32);
        lrun = lrun * al + rs;
        mrun = mn;

        uint2 w; w.x = cvtpk(p0, p1); w.y = cvtpk(p2, p3);
        *(uint2*)(rowp + ((lg << 3) ^ swz)) = w;
        uint2 z; z.x = 0; z.y = 0;
        *(uint2*)(rowp + ((32 + (lg << 3)) ^ swz)) = z;

        f32x4 al4;
#pragma unroll
        for (int r = 0; r < 4; ++r)
            al4[r] = __shfl(al, (lane & 48) + (lg << 2) + r);
#pragma unroll
        for (int j = 0; j < 4; ++j) acc_o[j] *= al4;

        const s16x8 pa0 = *(const s16x8*)(rowp + ((lg << 4) ^ swz));
#pragma unroll
        for (int dg = 0; dg < 4; ++dg) {
            s16x8 vb0 = (s16x8)(short)0;
            if (lg == 0) {
#pragma unroll
                for (int j = 0; j < 4; ++j)
                    vb0[j] = (short)vp[(size_t)(dg * 16 + lr) * 2048 + gall[j]];
            }
            acc_o[dg] = __builtin_amdgcn_mfma_f32_16x16x32_bf16(pa0, vb0, acc_o[dg], 0, 0, 0);
        }
    }

    // ---- normalize + write; SKIP rows in the gpos set (full-row path owns
    //      them; predicate is uniform across the row's lanes) ----
    {
        const float inv = 1.f / lrun;          // normalizer of query lr
#pragma unroll
        for (int r = 0; r < 4; ++r) {
            const float w0 = __shfl(inv, (lane & 48) + (lg << 2) + r);
            const int qrow = q0w + (lg << 2) + r;
            const bool isg = (qrow == gall[0]) || (qrow == gall[1]) ||
                             (qrow == gall[2]) || (qrow == gall[3]);
            if (!isg) {
                ushort* op = aout + (((size_t)b * L_ + qrow) * H_ + h) * Hd_;
#pragma unroll
                for (int dg = 0; dg < 4; ++dg)
                    op[dg * 16 + lr] = f2bf(acc_o[dg][r] * w0);
            }
        }
    }
#undef STAGE
}

// ---------------------------------------------------------------------------
extern "C" void kernel_launch(void* const* d_in, const int* in_sizes, int n_in,
                              void* d_out, int out_size, void* d_ws, size_t ws_size,
                              hipStream_t stream)
{
    const float* x  = (const float*)d_in[0];
    const int*   gp = (const int*)d_in[1];
    const float* Wq = (const float*)d_in[2];
    const float* bq = (const float*)d_in[3];
    const float* Wk = (const float*)d_in[4];
    const float* bk = (const float*)d_in[5];
    const float* Wv = (const float*)d_in[6];
    const float* bv = (const float*)d_in[7];
    const float* Wo = (const float*)d_in[8];
    const float* bo = (const float*)d_in[9];
    float* out = (float*)d_out;

    // workspace layout (ushort units)
    ushort* xb   = (ushort*)d_ws;                       // 4M (reused as awsb)
    ushort* awsb = xb;
    ushort* qws  = xb  + (size_t)4194304;               // 4M
    ushort* kws  = qws + (size_t)4194304;               // 1M
    ushort* vtws = kws + (size_t)1048576;               // 1M
    ushort* Wt   = vtws + (size_t)1048576;              // 1.5M
    ushort* Wot  = Wt  + (size_t)1572864;               // 1M
    float*  sct  = (float*)(Wot + (size_t)1048576);     // 128K floats

    k_prep_all<<<dim3(5376), 256, 0, stream>>>(x, xb, Wq, Wk, Wv, Wo, Wt, Wot, sct);

    k_gemm_bf16<<<dim3(32, 24), 256, 0, stream>>>(xb, Wt, 0, bq, bk, bv, sct,
                                                  qws, kws, vtws, (float*)0);

    k_attn_win<<<dim3(144, 4, 2), 256, 0, stream>>>(qws, kws, vtws, gp, awsb);

    k_gemm_bf16<<<dim3(32, 16), 256, 0, stream>>>(awsb, Wot, 1, bo, (const float*)0,
                                                  (const float*)0, (const float*)0,
                                                  (ushort*)0, (ushort*)0, (ushort*)0, out);
}

// Round 19
// 93.897 us; speedup vs baseline: 1.0048x; 1.0048x over previous
//
#include <hip/hip_runtime.h>
#include <math.h>

#define B_   2
#define L_   2048
#define D_   1024
#define H_   16
#define G_   4
#define Hd_  64
#define WIN_ 256

typedef float f4 __attribute__((ext_vector_type(4)));
typedef float f32x4 __attribute__((ext_vector_type(4)));
typedef short s16x8 __attribute__((ext_vector_type(8)));
typedef ushort u16x4 __attribute__((ext_vector_type(4)));

// ln(10000)/32
#define ROPE_LN 0.28782313662425575

__device__ __forceinline__ float bf2f(ushort u) {
    union { uint i; float f; } c; c.i = ((uint)u) << 16; return c.f;
}
__device__ __forceinline__ ushort f2bf(float f) {
    union { float f; uint i; } c; c.f = f;
    return (ushort)((c.i + 0x7FFFu + ((c.i >> 16) & 1u)) >> 16);
}
// pack two f32 -> two bf16 (RNE), single instruction
__device__ __forceinline__ uint cvtpk(float lo, float hi) {
    uint r;
    asm("v_cvt_pk_bf16_f32 %0, %1, %2" : "=v"(r) : "v"(lo), "v"(hi));
    return r;
}

// async global->LDS 16B copy: lds dest is wave-uniform base + lane*16
__device__ __forceinline__ void async_copy16(const ushort* g, ushort* l) {
    __builtin_amdgcn_global_load_lds(
        (const __attribute__((address_space(1))) void*)g,
        (__attribute__((address_space(3))) void*)l,
        16, 0, 0);
}

// ---------------------------------------------------------------------------
// Fused prep: blocks [0,4096) x-cast; [4096,5120) weight transpose+cast;
// [5120,5376) RoPE sin/cos table.
// ---------------------------------------------------------------------------
__global__ __launch_bounds__(256) void k_prep_all(
    const float* __restrict__ x, ushort* __restrict__ xb,
    const float* __restrict__ Wq, const float* __restrict__ Wk,
    const float* __restrict__ Wv, const float* __restrict__ Wo,
    ushort* __restrict__ Wt, ushort* __restrict__ Wot,
    float* __restrict__ sct)
{
    __shared__ __align__(16) float Ts[64][68];
    const int bid = blockIdx.x;
    const int tid = threadIdx.x;

    if (bid < 4096) {                       // ---- x cast ----
        const int idx = bid * 256 + tid;
        f4 v = ((const f4*)x)[idx];
        u16x4 o;
        o[0] = f2bf(v[0]); o[1] = f2bf(v[1]); o[2] = f2bf(v[2]); o[3] = f2bf(v[3]);
        ((u16x4*)xb)[idx] = o;
        return;
    }
    if (bid >= 5120) {                      // ---- sin/cos table ----
        const int idx = (bid - 5120) * 256 + tid;
        const int l = idx >> 5, m = idx & 31;
        const float invf = (float)exp(-ROPE_LN * (double)m);
        const float a = (float)l * invf;
        sct[l * 64 + m]      = cosf(a);
        sct[l * 64 + 32 + m] = sinf(a);
        return;
    }
    // ---- weight transpose+cast ----
    const int t = bid - 4096;
    const int z = t >> 8;
    const float* W; ushort* dst; int N, rowoff;
    if (z == 0)      { W = Wq; N = 1024; dst = Wt;  rowoff = 0;    }
    else if (z == 1) { W = Wk; N = 256;  dst = Wt;  rowoff = 1024; }
    else if (z == 2) { W = Wv; N = 256;  dst = Wt;  rowoff = 1280; }
    else             { W = Wo; N = 1024; dst = Wot; rowoff = 0;    }
    const int k0 = ((t >> 4) & 15) << 6;
    const int n0 = (t & 15) << 6;
    if (n0 >= N) return;
    const int rr = tid >> 4, cc4 = (tid & 15) << 2;
#pragma unroll
    for (int i = 0; i < 4; ++i) {
        const int r = rr + i * 16;
        *(f4*)&Ts[r][cc4] = *(const f4*)&W[(size_t)(k0 + r) * N + n0 + cc4];
    }
    __syncthreads();
#pragma unroll
    for (int i = 0; i < 4; ++i) {
        const int tr = rr + i * 16;
        u16x4 pk;
#pragma unroll
        for (int j = 0; j < 4; ++j) pk[j] = f2bf(Ts[cc4 + j][tr]);
        *(u16x4*)&dst[(size_t)(rowoff + n0 + tr) * 1024 + k0 + cc4] = pk;
    }
}

// ---------------------------------------------------------------------------
// bf16 MFMA GEMM: C[M,N] = A[M,1024] @ Bt[N,1024]^T.  128x64 tile, BK=64,
// global_load_lds(16B) staging, XOR-slot swizzle.
// mode 0: QKV epilogue (bias + RoPE from LDS table + scatter q/k/Vt bf16)
// mode 1: out-proj epilogue (bias + fp32 store)
// ---------------------------------------------------------------------------
__global__ __launch_bounds__(256) void k_gemm_bf16(
    const ushort* __restrict__ A, const ushort* __restrict__ Bt, int mode,
    const float* __restrict__ b0, const float* __restrict__ b1,
    const float* __restrict__ b2, const float* __restrict__ sct,
    ushort* __restrict__ qo, ushort* __restrict__ ko, ushort* __restrict__ vt,
    float* __restrict__ outp)
{
    __shared__ __align__(16) ushort LDSbuf[16384];    // As 8192 | Bs 4096 | (RoPE tab reuse)
    ushort* As = LDSbuf;
    ushort* Bs = LDSbuf + 8192;

    const int tid = threadIdx.x;
    const int wv = tid >> 6, lane = tid & 63, lr = lane & 15, lg = lane >> 4;
    const int wm = wv >> 1, wn = wv & 1;
    const int rblk = blockIdx.x << 7, cblk = blockIdx.y << 6;

    const ushort* agp[4]; ushort* alds[4];
#pragma unroll
    for (int i = 0; i < 4; ++i) {
        const int slot = wv * 256 + i * 64 + lane;
        const int r = slot >> 3, c = slot & 7;
        const int ss = c ^ (r & 7);
        agp[i] = A + (size_t)(rblk + r) * 1024 + ss * 8;
        alds[i] = As + (wv * 256 + i * 64) * 8;       // wave-uniform base
    }
    const ushort* bgp[2]; ushort* blds[2];
#pragma unroll
    for (int i = 0; i < 2; ++i) {
        const int slot = wv * 128 + i * 64 + lane;
        const int r = slot >> 3, c = slot & 7;
        const int ss = c ^ (r & 7);
        bgp[i] = Bt + (size_t)(cblk + r) * 1024 + ss * 8;
        blds[i] = Bs + (wv * 128 + i * 64) * 8;
    }

    f32x4 acc[4][2];
#pragma unroll
    for (int m = 0; m < 4; ++m)
#pragma unroll
        for (int n = 0; n < 2; ++n) acc[m][n] = (f32x4)0.f;

    for (int kt = 0; kt < 16; ++kt) {
        if (kt) __syncthreads();
        const int ko_ = kt * 64;
#pragma unroll
        for (int i = 0; i < 4; ++i) async_copy16(agp[i] + ko_, alds[i]);
#pragma unroll
        for (int i = 0; i < 2; ++i) async_copy16(bgp[i] + ko_, blds[i]);
        __syncthreads();

#pragma unroll
        for (int ks = 0; ks < 2; ++ks) {
            s16x8 aF[4], bF[2];
#pragma unroll
            for (int m = 0; m < 4; ++m) {
                const int r = wm * 64 + m * 16 + lr;
                const int c = (ks * 4 + lg) ^ (r & 7);
                aF[m] = *(const s16x8*)&As[r * 64 + c * 8];
            }
#pragma unroll
            for (int n = 0; n < 2; ++n) {
                const int r = wn * 32 + n * 16 + lr;
                const int c = (ks * 4 + lg) ^ (r & 7);
                bF[n] = *(const s16x8*)&Bs[r * 64 + c * 8];
            }
            __builtin_amdgcn_s_setprio(1);
#pragma unroll
            for (int m = 0; m < 4; ++m)
#pragma unroll
                for (int n = 0; n < 2; ++n)
                    acc[m][n] = __builtin_amdgcn_mfma_f32_16x16x32_bf16(aF[m], bF[n], acc[m][n], 0, 0, 0);
            __builtin_amdgcn_s_setprio(0);
        }
    }

    // ---- epilogue ----
    if (mode == 0) {
        const bool dorope = (cblk < 1280);
        float* tab = (float*)LDSbuf;
        if (dorope) {
            __syncthreads();
            const float* srcT = sct + (size_t)(rblk & 2047) * 64;
            for (int i = tid; i < 2048; i += 256)
                ((f4*)tab)[i] = ((const f4*)srcT)[i];
            __syncthreads();
        }
#pragma unroll
        for (int m = 0; m < 4; ++m) {
            const int row0 = rblk + wm * 64 + m * 16 + (lg << 2);
            const int bb = row0 >> 11, l0 = row0 & 2047;
            const int ll0 = row0 - rblk;
#pragma unroll
            for (int n = 0; n < 2; ++n) {
                const int col = cblk + wn * 32 + n * 16 + lr;
                float v_[4];
                const float bi = (col < 1024) ? b0[col]
                               : (col < 1280) ? b1[col - 1024] : b2[col - 1280];
#pragma unroll
                for (int rg = 0; rg < 4; ++rg) v_[rg] = acc[m][n][rg] + bi;
                if (dorope) {
                    const int mI = col & 31;
                    const float sgn = (lr & 1) ? 1.f : -1.f;
#pragma unroll
                    for (int rg = 0; rg < 4; ++rg) {
                        const float part = __shfl_xor(v_[rg], 1);
                        const float c_ = tab[(ll0 + rg) * 64 + mI];
                        const float s_ = tab[(ll0 + rg) * 64 + 32 + mI];
                        v_[rg] = v_[rg] * c_ + sgn * part * s_;
                    }
                }
                if (col < 1024) {
                    const int h = col >> 6, d = col & 63;
                    ushort* p = qo + (((size_t)(bb * 16 + h)) * 2048 + l0) * 64 + d;
#pragma unroll
                    for (int rg = 0; rg < 4; ++rg)
                        p[(size_t)rg * 64] = f2bf(v_[rg] * 0.125f);
                } else if (col < 1280) {
                    const int cl = col - 1024, g = cl >> 6, d = cl & 63;
                    ushort* p = ko + (((size_t)(bb * 4 + g)) * 2048 + l0) * 64 + d;
#pragma unroll
                    for (int rg = 0; rg < 4; ++rg)
                        p[(size_t)rg * 64] = f2bf(v_[rg]);
                } else {
                    const int cl = col - 1280, g = cl >> 6, d = cl & 63;
                    u16x4 pk;
#pragma unroll
                    for (int rg = 0; rg < 4; ++rg) pk[rg] = f2bf(v_[rg]);
                    *(u16x4*)(vt + ((size_t)(bb * 4 + g) * 64 + d) * 2048 + l0) = pk;
                }
            }
        }
    } else {
#pragma unroll
        for (int m = 0; m < 4; ++m) {
            const int row0 = rblk + wm * 64 + m * 16 + (lg << 2);
#pragma unroll
            for (int n = 0; n < 2; ++n) {
                const int col = cblk + wn * 32 + n * 16 + lr;
                const float bi = b0[col];
#pragma unroll
                for (int rg = 0; rg < 4; ++rg)
                    outp[(size_t)(row0 + rg) * 1024 + col] = acc[m][n][rg] + bi;
            }
        }
    }
}

// ---------------------------------------------------------------------------
// Windowed flash attention + merged full-row path.
// blocks x<128: windowed path (16 queries, group, batch; 4 waves = 4 heads;
//   K/V staged once per block via global_load_lds + XOR swizzle, double-
//   buffered; swapped-operand QK^T; in-lane softmax + 2 shfl; P via
//   v_cvt_pk_bf16_f32; XCD-aware qt swizzle).  Stores SKIP rows in the gpos
//   set (no ordering dependency on the full-row path).
// blocks x in [128,144): full-row attention for the <=4 unique global query
//   rows (one (h, gi) pair per block), LDS aliased into staging buffers.
// ---------------------------------------------------------------------------
__global__ __launch_bounds__(256, 4) void k_attn_win(
    const ushort* __restrict__ qb, const ushort* __restrict__ kb,
    const ushort* __restrict__ vtb, const int* __restrict__ gpos,
    ushort* __restrict__ aout)
{
    __shared__ __align__(16) ushort Ks[2][4096];   // 64r x 8 slots x 8 (8KB/buf)
    __shared__ __align__(16) ushort Vs[2][4096];
    __shared__ ushort Pl[4][1024];                 // per-wave P tile (swizzled)

    const int tid  = threadIdx.x;

    if (blockIdx.x >= 128) {
        // ================= merged full-row path =================
        const int e  = blockIdx.x - 128;           // 0..15
        const int gi = e >> 2;
        const int g  = blockIdx.y;
        const int h  = (g << 2) | (e & 3);
        const int b  = blockIdx.z;
        const int wv = tid >> 6, lane = tid & 63;
        const int lq = gpos[gi];
        for (int j = 0; j < gi; ++j)
            if (gpos[j] == lq) return;             // duplicate -> done

        float* Ps   = (float*)&Ks[0][0];           // 8 KB
        float* qrow = (float*)&Vs[0][0];           // 256 B
        float* red  = qrow + 64;                   // 16 B
        float* pacc = qrow + 128;                  // 1 KB: pacc[ch*64+d]

        const ushort* kbase = kb  + ((size_t)b * G_ + g) * (size_t)L_ * Hd_;
        const ushort* vbase = vtb + ((size_t)b * G_ + g) * (size_t)Hd_ * L_;

        if (tid < 64) qrow[tid] = bf2f(qb[(((size_t)b * H_ + h) * L_ + lq) * Hd_ + tid]);
        __syncthreads();

        float sc[8]; float lmax = -INFINITY;
#pragma unroll
        for (int c = 0; c < 8; ++c) {
            const int s = tid + (c << 8);
            const s16x8* kr = (const s16x8*)(kbase + (size_t)s * Hd_);
            float dot = 0.f;
#pragma unroll
            for (int d8 = 0; d8 < 8; ++d8) {
                s16x8 kv = kr[d8];
#pragma unroll
                for (int j = 0; j < 8; ++j) dot += qrow[d8 * 8 + j] * bf2f((ushort)kv[j]);
            }
            sc[c] = dot; lmax = fmaxf(lmax, dot);
        }
#pragma unroll
        for (int o = 32; o; o >>= 1) lmax = fmaxf(lmax, __shfl_xor(lmax, o));
        if (lane == 0) red[wv] = lmax;
        __syncthreads();
        const float M = fmaxf(fmaxf(red[0], red[1]), fmaxf(red[2], red[3]));
        __syncthreads();

        float ls = 0.f;
#pragma unroll
        for (int c = 0; c < 8; ++c) {
            const float p = __expf(sc[c] - M);
            Ps[tid + (c << 8)] = p;
            ls += p;
        }
#pragma unroll
        for (int o = 32; o; o >>= 1) ls += __shfl_xor(ls, o);
        if (lane == 0) red[wv] = ls;
        __syncthreads();
        const float S = red[0] + red[1] + red[2] + red[3];

        const int d = tid & 63, ch = tid >> 6;
        const ushort* vr = vbase + (size_t)d * L_ + (ch << 9);
        float a = 0.f;
        for (int s8 = 0; s8 < 64; ++s8) {
            s16x8 vv = ((const s16x8*)vr)[s8];
            const float* pp = &Ps[(ch << 9) + (s8 << 3)];
#pragma unroll
            for (int j = 0; j < 8; ++j) a += pp[j] * bf2f((ushort)vv[j]);
        }
        pacc[ch * 64 + d] = a;
        __syncthreads();
        if (tid < 64) {
            const float sum = pacc[0 * 64 + tid] + pacc[1 * 64 + tid]
                            + pacc[2 * 64 + tid] + pacc[3 * 64 + tid];
            aout[(((size_t)b * L_ + lq) * H_ + h) * Hd_ + tid] = f2bf(sum / S);
        }
        return;
    }

    // ================= windowed path =================
    const int wv   = tid >> 6, lane = tid & 63;
    const int lr   = lane & 15, lg = lane >> 4;
    const int qt = ((blockIdx.x & 7) << 4) | (blockIdx.x >> 3);  // XCD swizzle
    const int g = blockIdx.y, b = blockIdx.z;
    const int h  = (g << 2) + wv;             // this wave's head
    const int q0w = qt << 4;                  // 16 queries/block
    const int qpos = q0w + lr;                // this lane's softmax row

    const ushort* qp = qb  + (((size_t)b * H_ + h) * L_ + q0w) * Hd_;
    const ushort* kp = kb  + ((size_t)b * G_ + g) * (size_t)L_ * Hd_;
    const ushort* vp = vtb + ((size_t)b * G_ + g) * (size_t)Hd_ * L_;
    char* rowp = (char*)&Pl[wv][0] + (lr << 7);
    const int swz = (lr & 7) << 4;

    // staging geometry: 512 slots (64 rows x 8 x 16B) per matrix; this wave
    // covers slots [wv*128, wv*128+128) via 2 insts; lane -> slot base+lane.
    int sr[2], ssk[2];
    ushort* kl[2]; ushort* vl[2];
#pragma unroll
    for (int i = 0; i < 2; ++i) {
        const int slot = wv * 128 + i * 64 + lane;
        const int r = slot >> 3, c = slot & 7;
        sr[i] = r; ssk[i] = c ^ (r & 7);           // inverse-swizzled src slot
        kl[i] = ((ushort*)Ks) + (wv * 128 + i * 64) * 8;
        vl[i] = ((ushort*)Vs) + (wv * 128 + i * 64) * 8;
    }

#define STAGE(CUR, S0_) do {                                                  \
    _Pragma("unroll") for (int i = 0; i < 2; ++i) {                           \
        async_copy16(kp + ((size_t)(S0_) + sr[i]) * 64 + ssk[i] * 8,          \
                     kl[i] + (CUR) * 4096);                                   \
        async_copy16(vp + (size_t)sr[i] * 2048 + (S0_) + ssk[i] * 8,          \
                     vl[i] + (CUR) * 4096);                                   \
    } } while (0)

    const s16x8* qr = (const s16x8*)(qp + (size_t)lr * Hd_);
    const s16x8 qf0 = qr[lg], qf1 = qr[lg + 4];

    int gall[4];
#pragma unroll
    for (int j = 0; j < 4; ++j) gall[j] = gpos[j];
    bool uniq[4];
    uniq[0] = true;
    uniq[1] = (gall[1] != gall[0]);
    uniq[2] = (gall[2] != gall[0]) && (gall[2] != gall[1]);
    uniq[3] = (gall[3] != gall[0]) && (gall[3] != gall[1]) && (gall[3] != gall[2]);

    f32x4 acc_o[4];
#pragma unroll
    for (int j = 0; j < 4; ++j) acc_o[j] = (f32x4)0.f;
    float mrun = -INFINITY, lrun = 0.f;

    // window key tiles for queries [q0w, q0w+15]:
    const int t_lo = (q0w - WIN_ > 0) ? ((q0w - WIN_) >> 6) : 0;
    const int t_hi_f = (q0w + 15 + WIN_) >> 6;
    const int t_hi = (t_hi_f < (L_ >> 6) - 1) ? t_hi_f : (L_ >> 6) - 1;

    const int kc0 = lg ^ (lr & 7);            // swizzled read slots
    const int kc1 = (lg + 4) ^ (lr & 7);

    int cur = 0;
    STAGE(0, t_lo << 6);

    for (int t = t_lo; t <= t_hi; ++t) {
        const int s0 = t << 6;
        __syncthreads();                      // buf[cur] staged; prev consume done
        if (t < t_hi) STAGE(cur ^ 1, (t + 1) << 6);

        const ushort* Kb = ((const ushort*)Ks) + cur * 4096;
        const ushort* Vb = ((const ushort*)Vs) + cur * 4096;

        // ---- QK^T swapped, K frags from LDS ----
        f32x4 s[4];
#pragma unroll
        for (int gk = 0; gk < 4; ++gk) {
            const int gr = gk * 16 + lr;
            s16x8 kf0 = *(const s16x8*)&Kb[(gr * 8 + kc0) * 8];
            s16x8 kf1 = *(const s16x8*)&Kb[(gr * 8 + kc1) * 8];
            f32x4 tq = __builtin_amdgcn_mfma_f32_16x16x32_bf16(kf0, qf0, (f32x4)0.f, 0, 0, 0);
            s[gk]    = __builtin_amdgcn_mfma_f32_16x16x32_bf16(kf1, qf1, tq, 0, 0, 0);
        }

        // ---- V frags from LDS ----
        s16x8 vf0[4], vf1[4];
#pragma unroll
        for (int dg = 0; dg < 4; ++dg) {
            const int vrw = dg * 16 + lr;
            vf0[dg] = *(const s16x8*)&Vb[(vrw * 8 + kc0) * 8];
            vf1[dg] = *(const s16x8*)&Vb[(vrw * 8 + kc1) * 8];
        }

        // ---- mask (edge tiles only; wave-uniform test) ----
        if (s0 < q0w - 241 || s0 > q0w + 193) {
#pragma unroll
            for (int gk = 0; gk < 4; ++gk)
#pragma unroll
                for (int r2 = 0; r2 < 4; ++r2) {
                    const int key = s0 + gk * 16 + (lg << 2) + r2;
                    const int dlt = qpos - key;
                    if (dlt > WIN_ || dlt < -WIN_) s[gk][r2] = -INFINITY;
                }
        }

        // ---- online softmax: in-lane tree + 2 shfl ----
        float mx = fmaxf(fmaxf(s[0][0], s[0][1]), fmaxf(s[0][2], s[0][3]));
#pragma unroll
        for (int gk = 1; gk < 4; ++gk)
            mx = fmaxf(mx, fmaxf(fmaxf(s[gk][0], s[gk][1]), fmaxf(s[gk][2], s[gk][3])));
        mx = fmaxf(mx, __shfl_xor(mx, 16));
        mx = fmaxf(mx, __shfl_xor(mx, 32));
        const float mn = fmaxf(mrun, mx);
        const float al = __expf(mrun - mn);    // -inf -> 0, safe

        float rs = 0.f;
        uint pk0[4], pk1[4];
#pragma unroll
        for (int gk = 0; gk < 4; ++gk) {
            const float p0 = __expf(s[gk][0] - mn);
            const float p1 = __expf(s[gk][1] - mn);
            const float p2 = __expf(s[gk][2] - mn);
            const float p3 = __expf(s[gk][3] - mn);
            rs += (p0 + p1) + (p2 + p3);
            pk0[gk] = cvtpk(p0, p1);
            pk1[gk] = cvtpk(p2, p3);
        }
        rs += __shfl_xor(rs, 16);
        rs += __shfl_xor(rs, 32);
        lrun = lrun * al + rs;
        mrun = mn;

        // ---- P write: 4x 8B per lane, swizzled ----
#pragma unroll
        for (int gk = 0; gk < 4; ++gk) {
            uint2 w; w.x = pk0[gk]; w.y = pk1[gk];
            *(uint2*)(rowp + (((gk << 5) + (lg << 3)) ^ swz)) = w;
        }

        // ---- broadcast al to C-rows, rescale ----
        f32x4 al4;
#pragma unroll
        for (int r = 0; r < 4; ++r)
            al4[r] = __shfl(al, (lane & 48) + (lg << 2) + r);
#pragma unroll
        for (int j = 0; j < 4; ++j) acc_o[j] *= al4;

        // ---- PV ----
        const s16x8 pa0 = *(const s16x8*)(rowp + ((lg << 4) ^ swz));
        const s16x8 pa1 = *(const s16x8*)(rowp + ((64 + (lg << 4)) ^ swz));
        __builtin_amdgcn_s_setprio(1);
#pragma unroll
        for (int dg = 0; dg < 4; ++dg) {
            acc_o[dg] = __builtin_amdgcn_mfma_f32_16x16x32_bf16(pa0, vf0[dg], acc_o[dg], 0, 0, 0);
            acc_o[dg] = __builtin_amdgcn_mfma_f32_16x16x32_bf16(pa1, vf1[dg], acc_o[dg], 0, 0, 0);
        }
        __builtin_amdgcn_s_setprio(0);

        cur ^= 1;
    }

    // ---- global-column pseudo-tile (per wave, direct global; tiny) ----
    {
        const s16x8* kr = (const s16x8*)(kp + (size_t)gall[lr & 3] * 64);
        s16x8 kf0 = kr[lg], kf1 = kr[lg + 4];
        f32x4 tq = __builtin_amdgcn_mfma_f32_16x16x32_bf16(kf0, qf0, (f32x4)0.f, 0, 0, 0);
        f32x4 sv = __builtin_amdgcn_mfma_f32_16x16x32_bf16(kf1, qf1, tq, 0, 0, 0);

        // k = lg*4+r2 -> key gall[r2]; valid only lg==0 & unique & outside win
#pragma unroll
        for (int r2 = 0; r2 < 4; ++r2) {
            bool valid = (lg == 0) && uniq[r2];
            const int dlt = qpos - gall[r2];
            valid = valid && ((dlt > WIN_) || (dlt < -WIN_));
            if (!valid) sv[r2] = -INFINITY;
        }

        float mx = fmaxf(fmaxf(sv[0], sv[1]), fmaxf(sv[2], sv[3]));
        mx = fmaxf(mx, __shfl_xor(mx, 16));
        mx = fmaxf(mx, __shfl_xor(mx, 32));
        const float mn = fmaxf(mrun, mx);
        const float al = __expf(mrun - mn);
        const float p0 = __expf(sv[0] - mn);
        const float p1 = __expf(sv[1] - mn);
        const float p2 = __expf(sv[2] - mn);
        const float p3 = __expf(sv[3] - mn);
        float rs = (p0 + p1) + (p2 + p3);
        rs += __shfl_xor(rs, 16);
        rs += __shfl_xor(rs, 32);
        lrun = lrun * al + rs;
        mrun = mn;

        uint2 w; w.x = cvtpk(p0, p1); w.y = cvtpk(p2, p3);
        *(uint2*)(rowp + ((lg << 3) ^ swz)) = w;
        uint2 z; z.x = 0; z.y = 0;
        *(uint2*)(rowp + ((32 + (lg << 3)) ^ swz)) = z;

        f32x4 al4;
#pragma unroll
        for (int r = 0; r < 4; ++r)
            al4[r] = __shfl(al, (lane & 48) + (lg << 2) + r);
#pragma unroll
        for (int j = 0; j < 4; ++j) acc_o[j] *= al4;

        const s16x8 pa0 = *(const s16x8*)(rowp + ((lg << 4) ^ swz));
#pragma unroll
        for (int dg = 0; dg < 4; ++dg) {
            s16x8 vb0 = (s16x8)(short)0;
            if (lg == 0) {
#pragma unroll
                for (int j = 0; j < 4; ++j)
                    vb0[j] = (short)vp[(size_t)(dg * 16 + lr) * 2048 + gall[j]];
            }
            acc_o[dg] = __builtin_amdgcn_mfma_f32_16x16x32_bf16(pa0, vb0, acc_o[dg], 0, 0, 0);
        }
    }

    // ---- normalize + write; SKIP rows in the gpos set (full-row path owns
    //      them; predicate is uniform across the row's lanes) ----
    {
        const float inv = 1.f / lrun;          // normalizer of query lr
#pragma unroll
        for (int r = 0; r < 4; ++r) {
            const float w0 = __shfl(inv, (lane & 48) + (lg << 2) + r);
            const int qrow = q0w + (lg << 2) + r;
            const bool isg = (qrow == gall[0]) || (qrow == gall[1]) ||
                             (qrow == gall[2]) || (qrow == gall[3]);
            if (!isg) {
                ushort* op = aout + (((size_t)b * L_ + qrow) * H_ + h) * Hd_;
#pragma unroll
                for (int dg = 0; dg < 4; ++dg)
                    op[dg * 16 + lr] = f2bf(acc_o[dg][r] * w0);
            }
        }
    }
#undef STAGE
}

// ---------------------------------------------------------------------------
extern "C" void kernel_launch(void* const* d_in, const int* in_sizes, int n_in,
                              void* d_out, int out_size, void* d_ws, size_t ws_size,
                              hipStream_t stream)
{
    const float* x  = (const float*)d_in[0];
    const int*   gp = (const int*)d_in[1];
    const float* Wq = (const float*)d_in[2];
    const float* bq = (const float*)d_in[3];
    const float* Wk = (const float*)d_in[4];
    const float* bk = (const float*)d_in[5];
    const float* Wv = (const float*)d_in[6];
    const float* bv = (const float*)d_in[7];
    const float* Wo = (const float*)d_in[8];
    const float* bo = (const float*)d_in[9];
    float* out = (float*)d_out;

    // workspace layout (ushort units)
    ushort* xb   = (ushort*)d_ws;                       // 4M (reused as awsb)
    ushort* awsb = xb;
    ushort* qws  = xb  + (size_t)4194304;               // 4M
    ushort* kws  = qws + (size_t)4194304;               // 1M
    ushort* vtws = kws + (size_t)1048576;               // 1M
    ushort* Wt   = vtws + (size_t)1048576;              // 1.5M
    ushort* Wot  = Wt  + (size_t)1572864;               // 1M
    float*  sct  = (float*)(Wot + (size_t)1048576);     // 128K floats

    k_prep_all<<<dim3(5376), 256, 0, stream>>>(x, xb, Wq, Wk, Wv, Wo, Wt, Wot, sct);

    k_gemm_bf16<<<dim3(32, 24), 256, 0, stream>>>(xb, Wt, 0, bq, bk, bv, sct,
                                                  qws, kws, vtws, (float*)0);

    k_attn_win<<<dim3(144, 4, 2), 256, 0, stream>>>(qws, kws, vtws, gp, awsb);

    k_gemm_bf16<<<dim3(32, 16), 256, 0, stream>>>(awsb, Wot, 1, bo, (const float*)0,
                                                  (const float*)0, (const float*)0,
                                                  (ushort*)0, (ushort*)0, (ushort*)0, out);
}